// Round 3
// baseline (49.324 us; speedup 1.0000x reference)
//
#include <hip/hip_runtime.h>

// LBS skinning as bf16 MFMA GEMM, two-phase:
//   Phase 1 (pack_A, 11 blocks): pack A[k=4j+c][n=3b+i] = M[b,j,i,c] into
//     MFMA B-fragment lane order in d_ws (43 KB, L2-resident).
//   Phase 2 (skin_mfma): out[v,n] = sum_k X[v,k]*A[k,n],
//     X[v,4j+c] = w[v,j]*h_v[c], h=(x,y,z,1).  No LDS, no barriers.
// M=V=100000, N=96, K=208 (padded to 224 = 7 steps of 32)

typedef __attribute__((ext_vector_type(8))) short bf16x8;
typedef __attribute__((ext_vector_type(4))) float f32x4;

constexpr int J      = 52;
constexpr int KSTEPS = 7;    // 7 x K=32 (224, zero-padded past 208)
constexpr int NT     = 6;    // 6 n-tiles of 16 -> N=96
constexpr int MT     = 2;    // m-tiles (of 16 vertices) per wave
constexpr int WAVES  = 4;
constexpr int VPB    = WAVES * MT * 16;  // 128 vertices per block
constexpr int NSLOT  = KSTEPS * NT * 64; // 2688 fragment slots

__device__ __forceinline__ unsigned short f2bf(float f) {
    union { float f; unsigned u; } cv; cv.f = f;
    unsigned u = cv.u;
    u += 0x7FFFu + ((u >> 16) & 1u);   // round-to-nearest-even
    return (unsigned short)(u >> 16);
}

__global__ __launch_bounds__(256) void pack_A(
    const float* __restrict__ xf,
    bf16x8* __restrict__ Bp)
{
    const int slot = blockIdx.x * 256 + threadIdx.x;
    if (slot >= NSLOT) return;
    const int s    = slot / (NT * 64);
    const int rem  = slot - s * (NT * 64);
    const int t    = rem >> 6;
    const int l    = rem & 63;
    const int lgrp = l >> 4;
    const int lrow = l & 15;
    const int n = t * 16 + lrow;          // n = 3b + i, always < 96
    const int b = n / 3;
    const int i = n - 3 * b;
    const int j0 = s * 8 + lgrp * 2;      // elems 0-3 -> joint j0, 4-7 -> j0+1
    const float4* __restrict__ xf4 = reinterpret_cast<const float4*>(xf);
    float4 m0 = {0,0,0,0}, m1 = {0,0,0,0};
    if (j0 < J)     m0 = xf4[(b * J + j0) * 4 + i];
    if (j0 + 1 < J) m1 = xf4[(b * J + j0 + 1) * 4 + i];
    bf16x8 r;
    r[0] = (short)f2bf(m0.x); r[1] = (short)f2bf(m0.y);
    r[2] = (short)f2bf(m0.z); r[3] = (short)f2bf(m0.w);
    r[4] = (short)f2bf(m1.x); r[5] = (short)f2bf(m1.y);
    r[6] = (short)f2bf(m1.z); r[7] = (short)f2bf(m1.w);
    Bp[slot] = r;
}

__global__ __launch_bounds__(256) void skin_mfma(
    const float* __restrict__ verts,
    const float* __restrict__ weights,
    const bf16x8* __restrict__ Bp,
    float* __restrict__ out,
    int V)
{
    const int lane = threadIdx.x & 63;
    const int wid  = threadIdx.x >> 6;
    const int lgrp = lane >> 4;
    const int lrow = lane & 15;
    const int v0   = blockIdx.x * VPB + wid * (MT * 16);

    // one vertex per lane per m-tile (lanes 16-63 mirror 0-15's vertices)
    float hx[MT], hy[MT], hz[MT];
    int   vv[MT];
    bool  vok[MT];
#pragma unroll
    for (int mt = 0; mt < MT; ++mt) {
        const int v = v0 + mt * 16 + lrow;
        vv[mt]  = v;
        vok[mt] = (v < V);
        hx[mt] = vok[mt] ? verts[3 * (size_t)v + 0] : 0.f;
        hy[mt] = vok[mt] ? verts[3 * (size_t)v + 1] : 0.f;
        hz[mt] = vok[mt] ? verts[3 * (size_t)v + 2] : 0.f;
    }

    // hoist ALL weight loads (independent -> one latency, not 7)
    float2 wp[MT][KSTEPS];
#pragma unroll
    for (int mt = 0; mt < MT; ++mt)
#pragma unroll
        for (int s = 0; s < KSTEPS; ++s) {
            const int j0 = s * 8 + lgrp * 2;
            wp[mt][s] = (vok[mt] && j0 < J)
                ? *reinterpret_cast<const float2*>(weights + (size_t)vv[mt] * J + j0)
                : float2{0.f, 0.f};
        }

    f32x4 acc[MT][NT];
#pragma unroll
    for (int mt = 0; mt < MT; ++mt)
#pragma unroll
        for (int t = 0; t < NT; ++t)
            acc[mt][t] = f32x4{0.f, 0.f, 0.f, 0.f};

#pragma unroll
    for (int s = 0; s < KSTEPS; ++s) {
        bf16x8 afrag[MT];
#pragma unroll
        for (int mt = 0; mt < MT; ++mt) {
            const float w0 = wp[mt][s].x, w1 = wp[mt][s].y;
            bf16x8 a;
            a[0] = (short)f2bf(w0 * hx[mt]); a[1] = (short)f2bf(w0 * hy[mt]);
            a[2] = (short)f2bf(w0 * hz[mt]); a[3] = (short)f2bf(w0);
            a[4] = (short)f2bf(w1 * hx[mt]); a[5] = (short)f2bf(w1 * hy[mt]);
            a[6] = (short)f2bf(w1 * hz[mt]); a[7] = (short)f2bf(w1);
            afrag[mt] = a;
        }
#pragma unroll
        for (int t = 0; t < NT; ++t) {
            const bf16x8 bfrag = Bp[(s * NT + t) * 64 + lane];  // coalesced, L2-hot
            acc[0][t] = __builtin_amdgcn_mfma_f32_16x16x32_bf16(
                afrag[0], bfrag, acc[0][t], 0, 0, 0);
            acc[1][t] = __builtin_amdgcn_mfma_f32_16x16x32_bf16(
                afrag[1], bfrag, acc[1][t], 0, 0, 0);
        }
    }

    // ---- store: lane holds D[v0m + lgrp*4 + r][t*16 + lrow], r=0..3 ----
#pragma unroll
    for (int mt = 0; mt < MT; ++mt) {
        const int vbase = v0 + mt * 16 + lgrp * 4;
#pragma unroll
        for (int t = 0; t < NT; ++t) {
            const int n = t * 16 + lrow;
            const int b = n / 3;
            const int i = n - 3 * b;
            const size_t base = (size_t)b * (size_t)V * 3 + i;
#pragma unroll
            for (int r = 0; r < 4; ++r) {
                const int v = vbase + r;
                if (v < V) out[base + (size_t)v * 3] = acc[mt][t][r];
            }
        }
    }
}

extern "C" void kernel_launch(void* const* d_in, const int* in_sizes, int n_in,
                              void* d_out, int out_size, void* d_ws, size_t ws_size,
                              hipStream_t stream)
{
    const float* verts   = (const float*)d_in[0];
    const float* weights = (const float*)d_in[1];
    const float* xf      = (const float*)d_in[2];
    float* out = (float*)d_out;

    const int V = in_sizes[0] / 3;   // 100000
    bf16x8* Bp = (bf16x8*)d_ws;      // 43008 bytes

    pack_A<<<(NSLOT + 255) / 256, 256, 0, stream>>>(xf, Bp);
    const int nblocks = (V + VPB - 1) / VPB;
    skin_mfma<<<nblocks, 256, 0, stream>>>(verts, weights, Bp, out, V);
}

// Round 4
// 33.743 us; speedup vs baseline: 1.4618x; 1.4618x over previous
//
#include <hip/hip_runtime.h>

// LBS skinning as bf16 MFMA GEMM (SWAPPED operands), two-phase:
//   Phase 1 (pack_A): pack A[k=4j+c][n=3b+i] = M[b,j,i,c] into MFMA
//     A-operand fragment lane order in d_ws (43 KB, L2-resident).
//   Phase 2 (skin_mfma): D[n][v] = sum_k A[k,n] * X[v,k],
//     X[v,4j+c] = w[v,j]*h_v[c], h=(x,y,z,1).
//   mfma(A=matfrag, B=xfrag): D col(lane&15) = VERTEX -> coalesced-ish stores.
// V=100000, N=96, K=208 (padded to 224 = 7 steps of 32)

typedef __attribute__((ext_vector_type(8))) short bf16x8;
typedef __attribute__((ext_vector_type(4))) float f32x4;

constexpr int J      = 52;
constexpr int KSTEPS = 7;    // 7 x K=32 (224, zero-padded past 208)
constexpr int NT     = 6;    // 6 n-tiles of 16 -> N=96
constexpr int WAVES  = 4;
constexpr int VPB    = WAVES * 16;       // 64 vertices per block (16/wave)
constexpr int NSLOT  = KSTEPS * NT * 64; // 2688 fragment slots

__device__ __forceinline__ unsigned short f2bf(float f) {
    union { float f; unsigned u; } cv; cv.f = f;
    unsigned u = cv.u;
    u += 0x7FFFu + ((u >> 16) & 1u);   // round-to-nearest-even
    return (unsigned short)(u >> 16);
}

__global__ __launch_bounds__(256) void pack_A(
    const float* __restrict__ xf,
    bf16x8* __restrict__ Bp)
{
    const int slot = blockIdx.x * 256 + threadIdx.x;
    if (slot >= NSLOT) return;
    const int s    = slot / (NT * 64);
    const int rem  = slot - s * (NT * 64);
    const int t    = rem >> 6;
    const int l    = rem & 63;
    const int lgrp = l >> 4;
    const int lrow = l & 15;
    const int n = t * 16 + lrow;          // n = 3b + i, always < 96
    const int b = n / 3;
    const int i = n - 3 * b;
    const int j0 = s * 8 + lgrp * 2;      // elems 0-3 -> joint j0, 4-7 -> j0+1
    const float4* __restrict__ xf4 = reinterpret_cast<const float4*>(xf);
    float4 m0 = {0,0,0,0}, m1 = {0,0,0,0};
    if (j0 < J)     m0 = xf4[(b * J + j0) * 4 + i];
    if (j0 + 1 < J) m1 = xf4[(b * J + j0 + 1) * 4 + i];
    bf16x8 r;
    r[0] = (short)f2bf(m0.x); r[1] = (short)f2bf(m0.y);
    r[2] = (short)f2bf(m0.z); r[3] = (short)f2bf(m0.w);
    r[4] = (short)f2bf(m1.x); r[5] = (short)f2bf(m1.y);
    r[6] = (short)f2bf(m1.z); r[7] = (short)f2bf(m1.w);
    Bp[slot] = r;
}

__global__ __launch_bounds__(256) void skin_mfma(
    const float* __restrict__ verts,
    const float* __restrict__ weights,
    const bf16x8* __restrict__ Bp,
    float* __restrict__ out,
    int V)
{
    const int lane = threadIdx.x & 63;
    const int wid  = threadIdx.x >> 6;
    const int lgrp = lane >> 4;
    const int lrow = lane & 15;

    // one vertex per lane (16 per wave); lanes 16-63 mirror lanes 0-15's verts
    const int  v   = blockIdx.x * VPB + wid * 16 + lrow;
    const bool vok = (v < V);

    const float hx = vok ? verts[3 * (size_t)v + 0] : 0.f;
    const float hy = vok ? verts[3 * (size_t)v + 1] : 0.f;
    const float hz = vok ? verts[3 * (size_t)v + 2] : 0.f;

    // hoist ALL weight loads (independent -> one latency)
    float2 wp[KSTEPS];
#pragma unroll
    for (int s = 0; s < KSTEPS; ++s) {
        const int j0 = s * 8 + lgrp * 2;
        wp[s] = (vok && j0 < J)
            ? *reinterpret_cast<const float2*>(weights + (size_t)v * J + j0)
            : float2{0.f, 0.f};
    }

    f32x4 acc[NT];
#pragma unroll
    for (int t = 0; t < NT; ++t) acc[t] = f32x4{0.f, 0.f, 0.f, 0.f};

#pragma unroll
    for (int s = 0; s < KSTEPS; ++s) {
        const float w0 = wp[s].x, w1 = wp[s].y;
        bf16x8 xfrag;
        xfrag[0] = (short)f2bf(w0 * hx); xfrag[1] = (short)f2bf(w0 * hy);
        xfrag[2] = (short)f2bf(w0 * hz); xfrag[3] = (short)f2bf(w0);
        xfrag[4] = (short)f2bf(w1 * hx); xfrag[5] = (short)f2bf(w1 * hy);
        xfrag[6] = (short)f2bf(w1 * hz); xfrag[7] = (short)f2bf(w1);
#pragma unroll
        for (int t = 0; t < NT; ++t) {
            const bf16x8 matfrag = Bp[(s * NT + t) * 64 + lane];  // coalesced, L2-hot
            // SWAPPED: A = matrix (rows n), B = X (cols v)
            acc[t] = __builtin_amdgcn_mfma_f32_16x16x32_bf16(
                matfrag, xfrag, acc[t], 0, 0, 0);
        }
    }

    // ---- store: lane holds D[n = 16t + lgrp*4 + r][v], v = col = lane&15 ----
    if (vok) {
        const size_t v3 = (size_t)v * 3;
#pragma unroll
        for (int t = 0; t < NT; ++t) {
#pragma unroll
            for (int r = 0; r < 4; ++r) {
                const int n = 16 * t + lgrp * 4 + r;
                const int b = n / 3;
                const int i = n - 3 * b;
                out[(size_t)b * (size_t)V * 3 + v3 + i] = acc[t][r];
            }
        }
    }
}

extern "C" void kernel_launch(void* const* d_in, const int* in_sizes, int n_in,
                              void* d_out, int out_size, void* d_ws, size_t ws_size,
                              hipStream_t stream)
{
    const float* verts   = (const float*)d_in[0];
    const float* weights = (const float*)d_in[1];
    const float* xf      = (const float*)d_in[2];
    float* out = (float*)d_out;

    const int V = in_sizes[0] / 3;   // 100000
    bf16x8* Bp = (bf16x8*)d_ws;      // 43008 bytes

    pack_A<<<(NSLOT + 255) / 256, 256, 0, stream>>>(xf, Bp);
    const int nblocks = (V + VPB - 1) / VPB;
    skin_mfma<<<nblocks, 256, 0, stream>>>(verts, weights, Bp, out, V);
}

// Round 5
// 29.864 us; speedup vs baseline: 1.6516x; 1.1299x over previous
//
#include <hip/hip_runtime.h>

// LBS skinning as bf16 MFMA GEMM (swapped operands), two-phase:
//   Phase 1 (pack_A): pack A[k=4j+c][n=3b+i] = M[b,j,i,c] into MFMA
//     A-operand fragment lane order in d_ws (43 KB, L2-resident).
//   Phase 2 (skin_mfma): D[n][v] = sum_k A[k,n] * X[v,k],
//     X[v,4j+c] = w[v,j]*h_v[c], h=(x,y,z,1).
//   Per block: stage A-frags + weight rows + verts into LDS via
//   global_load_lds (linear, width 16), then MT=2 m-tiles per wave reuse
//   each A-fragment (halves A-read traffic, moves it L2 -> LDS).
// V=100000, N=96, K=208 (padded to 224 = 7 steps of 32)

typedef __attribute__((ext_vector_type(8))) short bf16x8;
typedef __attribute__((ext_vector_type(4))) float f32x4;

constexpr int J      = 52;
constexpr int KSTEPS = 7;                 // 7 x K=32 (224, zero-padded past 208)
constexpr int NT     = 6;                 // 6 n-tiles of 16 -> N=96
constexpr int WAVES  = 4;
constexpr int MT     = 2;                 // m-tiles (16 verts) per wave
constexpr int VPW    = MT * 16;           // 32 verts per wave
constexpr int VPB    = WAVES * VPW;       // 128 verts per block
constexpr int NSLOT  = KSTEPS * NT * 64;  // 2688 fragment slots
constexpr int BP_B   = NSLOT * 16;        // 43008 B
constexpr int W_B    = VPB * J * 4;       // 26624 B
constexpr int VT_B   = VPB * 3 * 4;       // 1536 B

typedef const __attribute__((address_space(1))) char* gas1_t;
typedef __attribute__((address_space(3))) char* las3_t;

__device__ __forceinline__ unsigned short f2bf(float f) {
    union { float f; unsigned u; } cv; cv.f = f;
    unsigned u = cv.u;
    u += 0x7FFFu + ((u >> 16) & 1u);   // round-to-nearest-even
    return (unsigned short)(u >> 16);
}

__global__ __launch_bounds__(256) void pack_A(
    const float* __restrict__ xf,
    bf16x8* __restrict__ Bp)
{
    const int slot = blockIdx.x * 256 + threadIdx.x;
    if (slot >= NSLOT) return;
    const int s    = slot / (NT * 64);
    const int rem  = slot - s * (NT * 64);
    const int t    = rem >> 6;
    const int l    = rem & 63;
    const int lgrp = l >> 4;
    const int lrow = l & 15;
    const int n = t * 16 + lrow;          // n = 3b + i, always < 96
    const int b = n / 3;
    const int i = n - 3 * b;
    const int j0 = s * 8 + lgrp * 2;      // elems 0-3 -> joint j0, 4-7 -> j0+1
    const float4* __restrict__ xf4 = reinterpret_cast<const float4*>(xf);
    float4 m0 = {0,0,0,0}, m1 = {0,0,0,0};
    if (j0 < J)     m0 = xf4[(b * J + j0) * 4 + i];
    if (j0 + 1 < J) m1 = xf4[(b * J + j0 + 1) * 4 + i];
    bf16x8 r;
    r[0] = (short)f2bf(m0.x); r[1] = (short)f2bf(m0.y);
    r[2] = (short)f2bf(m0.z); r[3] = (short)f2bf(m0.w);
    r[4] = (short)f2bf(m1.x); r[5] = (short)f2bf(m1.y);
    r[6] = (short)f2bf(m1.z); r[7] = (short)f2bf(m1.w);
    Bp[slot] = r;
}

__global__ __launch_bounds__(256) void skin_mfma(
    const float* __restrict__ verts,
    const float* __restrict__ weights,
    const bf16x8* __restrict__ Bp,
    float* __restrict__ out,
    int V)
{
    __shared__ __align__(16) char smem[BP_B + W_B + VT_B];   // 71168 B
    char* sBp = smem;
    char* sW  = smem + BP_B;
    char* sVt = smem + BP_B + W_B;

    const int tid  = threadIdx.x;
    const int lane = tid & 63;
    const int wid  = tid >> 6;
    const int lgrp = lane >> 4;
    const int lrow = lane & 15;
    const int v0   = blockIdx.x * VPB;

    // ---- stage packed A: 43008 B, linear copy, wave-striped 1KB chunks ----
    {
        const char* g = (const char*)Bp;
        for (int p = wid; p < BP_B / 1024; p += WAVES) {
            __builtin_amdgcn_global_load_lds(
                (gas1_t)(g + p * 1024 + lane * 16),
                (las3_t)(sBp + p * 1024), 16, 0, 0);
        }
    }
    // ---- stage this block's weight rows: 26624 B contiguous, OOB-guarded ----
    {
        const char* g = (const char*)(weights + (size_t)v0 * J);
        const long long valid = ((long long)V - v0) * J * 4;   // bytes from g
        for (int p = wid; p < W_B / 1024; p += WAVES) {
            const int off = p * 1024 + lane * 16;
            if (off + 16 <= valid) {
                __builtin_amdgcn_global_load_lds(
                    (gas1_t)(g + off), (las3_t)(sW + p * 1024), 16, 0, 0);
            }
        }
    }
    // ---- stage verts: 384 floats, zero-pad OOB ----
    for (int i = tid; i < VPB * 3; i += 256) {
        const long long idx = (long long)v0 * 3 + i;
        float val = (idx < (long long)V * 3) ? verts[idx] : 0.f;
        *(float*)(sVt + i * 4) = val;
    }
    __syncthreads();

    // ---- per-wave: 2 m-tiles of 16 verts; lanes 16-63 mirror lanes 0-15 ----
    const int vw0 = wid * VPW;    // block-local base vertex of this wave
    float hx[MT], hy[MT], hz[MT];
    int   vv[MT];
    bool  vok[MT];
#pragma unroll
    for (int mt = 0; mt < MT; ++mt) {
        const int bl = vw0 + mt * 16 + lrow;
        vv[mt]  = v0 + bl;
        vok[mt] = vv[mt] < V;
        const float* vp = (const float*)(sVt + bl * 12);
        hx[mt] = vp[0]; hy[mt] = vp[1]; hz[mt] = vp[2];
    }

    float2 wv[MT][KSTEPS];
#pragma unroll
    for (int mt = 0; mt < MT; ++mt) {
        const int bl = vw0 + mt * 16 + lrow;
#pragma unroll
        for (int s = 0; s < KSTEPS; ++s) {
            const int j0 = s * 8 + lgrp * 2;
            wv[mt][s] = (j0 < J)
                ? *(const float2*)(sW + ((size_t)bl * J + j0) * 4)
                : float2{0.f, 0.f};
        }
    }

    f32x4 acc[MT][NT];
#pragma unroll
    for (int mt = 0; mt < MT; ++mt)
#pragma unroll
        for (int t = 0; t < NT; ++t)
            acc[mt][t] = f32x4{0.f, 0.f, 0.f, 0.f};

#pragma unroll
    for (int s = 0; s < KSTEPS; ++s) {
        bf16x8 frag[NT];
#pragma unroll
        for (int t = 0; t < NT; ++t)
            frag[t] = *(const bf16x8*)(sBp + ((s * NT + t) * 64 + lane) * 16);
#pragma unroll
        for (int mt = 0; mt < MT; ++mt) {
            const float w0 = wv[mt][s].x, w1 = wv[mt][s].y;
            bf16x8 xf8;
            xf8[0] = (short)f2bf(w0 * hx[mt]); xf8[1] = (short)f2bf(w0 * hy[mt]);
            xf8[2] = (short)f2bf(w0 * hz[mt]); xf8[3] = (short)f2bf(w0);
            xf8[4] = (short)f2bf(w1 * hx[mt]); xf8[5] = (short)f2bf(w1 * hy[mt]);
            xf8[6] = (short)f2bf(w1 * hz[mt]); xf8[7] = (short)f2bf(w1);
#pragma unroll
            for (int t = 0; t < NT; ++t) {
                // SWAPPED: A = matrix (rows n), B = X (cols v)
                acc[mt][t] = __builtin_amdgcn_mfma_f32_16x16x32_bf16(
                    frag[t], xf8, acc[mt][t], 0, 0, 0);
            }
        }
    }

    // ---- store: lane holds D[n = 16t + lgrp*4 + r][v], v = col = lane&15 ----
#pragma unroll
    for (int mt = 0; mt < MT; ++mt) {
        if (!vok[mt]) continue;
        const size_t v3 = (size_t)vv[mt] * 3;
#pragma unroll
        for (int t = 0; t < NT; ++t) {
#pragma unroll
            for (int r = 0; r < 4; ++r) {
                const int n = 16 * t + lgrp * 4 + r;
                const int b = n / 3;
                const int i = n - 3 * b;
                out[(size_t)b * (size_t)V * 3 + v3 + i] = acc[mt][t][r];
            }
        }
    }
}

extern "C" void kernel_launch(void* const* d_in, const int* in_sizes, int n_in,
                              void* d_out, int out_size, void* d_ws, size_t ws_size,
                              hipStream_t stream)
{
    const float* verts   = (const float*)d_in[0];
    const float* weights = (const float*)d_in[1];
    const float* xf      = (const float*)d_in[2];
    float* out = (float*)d_out;

    const int V = in_sizes[0] / 3;   // 100000
    bf16x8* Bp = (bf16x8*)d_ws;      // 43008 bytes

    pack_A<<<(NSLOT + 255) / 256, 256, 0, stream>>>(xf, Bp);
    const int nblocks = (V + VPB - 1) / VPB;
    skin_mfma<<<nblocks, 256, 0, stream>>>(verts, weights, Bp, out, V);
}

// Round 6
// 29.028 us; speedup vs baseline: 1.6992x; 1.0288x over previous
//
#include <hip/hip_runtime.h>
#include <hip/hip_bf16.h>

// LBS skinning as bf16 MFMA GEMM (swapped operands), two-phase:
//   Phase 1 (pack_A): pack A[k=4j+c][n=3b+i] = M[b,j,i,c] into MFMA
//     A-operand fragment lane order in d_ws (43 KB, L2-resident).
//   Phase 2 (skin_mfma): D[n][v] = sum_k A[k,n] * X[v,k],
//     X[v,4j+c] = w[v,j]*h_v[c], h=(x,y,z,1).
//   Per block: ONLY packed A staged to LDS (43 KB -> 3 blocks/CU); weights
//   and verts go straight to registers, issued concurrently with the
//   global_load_lds stage so the barrier pays one latency, not three.
// V=100000, N=96, K=208 (padded to 224 = 7 steps of 32)

typedef __attribute__((ext_vector_type(8))) short bf16x8;
typedef __attribute__((ext_vector_type(4))) float f32x4;

constexpr int J      = 52;
constexpr int KSTEPS = 7;                 // 7 x K=32 (224, zero-padded past 208)
constexpr int NT     = 6;                 // 6 n-tiles of 16 -> N=96
constexpr int WAVES  = 4;
constexpr int MT     = 2;                 // m-tiles (16 verts) per wave
constexpr int VPW    = MT * 16;           // 32 verts per wave
constexpr int VPB    = WAVES * VPW;       // 128 verts per block
constexpr int NSLOT  = KSTEPS * NT * 64;  // 2688 fragment slots
constexpr int BP_B   = NSLOT * 16;        // 43008 B

typedef const __attribute__((address_space(1))) char* gas1_t;
typedef __attribute__((address_space(3))) char* las3_t;

__device__ __forceinline__ unsigned pk2(float a, float b) {
    // compiler folds to v_cvt_pk_bf16_f32 (RNE)
    __hip_bfloat162 h = __float22bfloat162_rn(make_float2(a, b));
    return *reinterpret_cast<unsigned*>(&h);
}

__global__ __launch_bounds__(256) void pack_A(
    const float* __restrict__ xf,
    bf16x8* __restrict__ Bp)
{
    const int slot = blockIdx.x * 256 + threadIdx.x;
    if (slot >= NSLOT) return;
    const int s    = slot / (NT * 64);
    const int rem  = slot - s * (NT * 64);
    const int t    = rem >> 6;
    const int l    = rem & 63;
    const int lgrp = l >> 4;
    const int lrow = l & 15;
    const int n = t * 16 + lrow;          // n = 3b + i, always < 96
    const int b = n / 3;
    const int i = n - 3 * b;
    const int j0 = s * 8 + lgrp * 2;      // elems 0-3 -> joint j0, 4-7 -> j0+1
    const float4* __restrict__ xf4 = reinterpret_cast<const float4*>(xf);
    float4 m0 = {0,0,0,0}, m1 = {0,0,0,0};
    if (j0 < J)     m0 = xf4[(b * J + j0) * 4 + i];
    if (j0 + 1 < J) m1 = xf4[(b * J + j0 + 1) * 4 + i];
    union { bf16x8 v; unsigned w[4]; } r;
    r.w[0] = pk2(m0.x, m0.y); r.w[1] = pk2(m0.z, m0.w);
    r.w[2] = pk2(m1.x, m1.y); r.w[3] = pk2(m1.z, m1.w);
    Bp[slot] = r.v;
}

__global__ __launch_bounds__(256) void skin_mfma(
    const float* __restrict__ verts,
    const float* __restrict__ weights,
    const bf16x8* __restrict__ Bp,
    float* __restrict__ out,
    int V)
{
    __shared__ __align__(16) char sBp[BP_B];   // 43008 B -> 3 blocks/CU

    const int tid  = threadIdx.x;
    const int lane = tid & 63;
    const int wid  = tid >> 6;
    const int lgrp = lane >> 4;
    const int lrow = lane & 15;
    const int v0   = blockIdx.x * VPB;

    // ---- issue A-stage first: 43008 B linear, wave-striped 1KB chunks ----
    {
        const char* g = (const char*)Bp;
        for (int p = wid; p < BP_B / 1024; p += WAVES) {
            __builtin_amdgcn_global_load_lds(
                (gas1_t)(g + p * 1024 + lane * 16),
                (las3_t)(sBp + p * 1024), 16, 0, 0);
        }
    }

    // ---- reg loads issued in the stage's shadow (verts + weights) ----
    int   vv[MT];
    bool  vok[MT];
    float hx[MT], hy[MT], hz[MT];
    float2 wv[MT][KSTEPS];
#pragma unroll
    for (int mt = 0; mt < MT; ++mt) {
        const int v = v0 + wid * VPW + mt * 16 + lrow;
        vv[mt]  = v;
        vok[mt] = (v < V);
        const int vcl = vok[mt] ? v : (V - 1);   // clamp: garbage lanes never stored,
                                                 // and can't pollute valid D columns
        hx[mt] = verts[3 * (size_t)vcl + 0];
        hy[mt] = verts[3 * (size_t)vcl + 1];
        hz[mt] = verts[3 * (size_t)vcl + 2];
        const float* wr = weights + (size_t)vcl * J;
#pragma unroll
        for (int s = 0; s < KSTEPS; ++s) {
            const int j0 = s * 8 + lgrp * 2;
            wv[mt][s] = (j0 < J) ? *(const float2*)(wr + j0) : float2{0.f, 0.f};
        }
    }

    __syncthreads();

    // ---- k-loop: pure LDS + VALU + MFMA ----
    f32x4 acc[MT][NT];
#pragma unroll
    for (int mt = 0; mt < MT; ++mt)
#pragma unroll
        for (int t = 0; t < NT; ++t)
            acc[mt][t] = f32x4{0.f, 0.f, 0.f, 0.f};

#pragma unroll
    for (int s = 0; s < KSTEPS; ++s) {
        bf16x8 frag[NT];
#pragma unroll
        for (int t = 0; t < NT; ++t)
            frag[t] = *(const bf16x8*)(sBp + ((s * NT + t) * 64 + lane) * 16);
#pragma unroll
        for (int mt = 0; mt < MT; ++mt) {
            const float w0 = wv[mt][s].x, w1 = wv[mt][s].y;
            union { bf16x8 v; unsigned w[4]; } xf8;
            xf8.w[0] = pk2(w0 * hx[mt], w0 * hy[mt]);
            xf8.w[1] = pk2(w0 * hz[mt], w0);
            xf8.w[2] = pk2(w1 * hx[mt], w1 * hy[mt]);
            xf8.w[3] = pk2(w1 * hz[mt], w1);
#pragma unroll
            for (int t = 0; t < NT; ++t) {
                // SWAPPED: A = matrix (rows n), B = X (cols v)
                acc[mt][t] = __builtin_amdgcn_mfma_f32_16x16x32_bf16(
                    frag[t], xf8.v, acc[mt][t], 0, 0, 0);
            }
        }
    }

    // ---- store: lane holds D[n = 16t + lgrp*4 + r][v], v = col = lane&15 ----
#pragma unroll
    for (int mt = 0; mt < MT; ++mt) {
        if (!vok[mt]) continue;
        const size_t v3 = (size_t)vv[mt] * 3;
#pragma unroll
        for (int t = 0; t < NT; ++t) {
#pragma unroll
            for (int r = 0; r < 4; ++r) {
                const int n = 16 * t + lgrp * 4 + r;
                const int b = n / 3;
                const int i = n - 3 * b;
                out[(size_t)b * (size_t)V * 3 + v3 + i] = acc[mt][t][r];
            }
        }
    }
}

extern "C" void kernel_launch(void* const* d_in, const int* in_sizes, int n_in,
                              void* d_out, int out_size, void* d_ws, size_t ws_size,
                              hipStream_t stream)
{
    const float* verts   = (const float*)d_in[0];
    const float* weights = (const float*)d_in[1];
    const float* xf      = (const float*)d_in[2];
    float* out = (float*)d_out;

    const int V = in_sizes[0] / 3;   // 100000
    bf16x8* Bp = (bf16x8*)d_ws;      // 43008 bytes

    pack_A<<<(NSLOT + 255) / 256, 256, 0, stream>>>(xf, Bp);
    const int nblocks = (V + VPB - 1) / VPB;
    skin_mfma<<<nblocks, 256, 0, stream>>>(verts, weights, Bp, out, V);
}

// Round 7
// 28.702 us; speedup vs baseline: 1.7185x; 1.0113x over previous
//
#include <hip/hip_runtime.h>
#include <hip/hip_bf16.h>

// LBS skinning as bf16 MFMA GEMM (swapped operands), two-phase:
//   Phase 1 (pack_A): pack A[k=4j+c][n=3b+i] = M[b,j,i,c] into MFMA
//     A-operand fragment lane order in d_ws (COMPACT: 39952 B).
//   Phase 2 (skin_mfma): D[n][v] = sum_k A[k,n] * X[v,k],
//     X[v,4j+c] = w[v,j]*h_v[c], h=(x,y,z,1).
//   Compact layout: s=0..5 full (64 lanes); s=6 stores only lgrp 0/1
//   (j0=48,50 -- lgrp 2/3 would be j0>=52 = zero padding) + one broadcast
//   zero slot. LDS = 40960 B -> exactly 4 blocks/CU; with
//   __launch_bounds__(256,4) VGPR caps at 128 -> 16 waves/CU.
// V=100000, N=96, K=208 (padded to 224 = 7 steps of 32)

typedef __attribute__((ext_vector_type(8))) short bf16x8;
typedef __attribute__((ext_vector_type(4))) float f32x4;

constexpr int J      = 52;
constexpr int KSTEPS = 7;
constexpr int NT     = 6;                  // 6 n-tiles of 16 -> N=96
constexpr int WAVES  = 4;
constexpr int MT     = 2;                  // m-tiles (16 verts) per wave
constexpr int VPW    = MT * 16;            // 32 verts per wave
constexpr int VPB    = WAVES * VPW;        // 128 verts per block

constexpr int SLOTS_FULL = 6 * NT * 64;    // 2304 slots, s = 0..5
constexpr int SLOTS_S6   = NT * 32;        // 192 slots, s = 6 (lgrp 0/1 only)
constexpr int ZSLOT      = SLOTS_FULL + SLOTS_S6;  // 2496: broadcast zero slot
constexpr int NSLOT      = ZSLOT + 1;      // 2497 slots written by pack_A
constexpr int S6_BASE_B  = SLOTS_FULL * 16;        // 36864
constexpr int Z_B        = ZSLOT * 16;             // 39936
constexpr int LDS_B      = 40960;          // staged bytes (tail 1 KB unread)

typedef const __attribute__((address_space(1))) char* gas1_t;
typedef __attribute__((address_space(3))) char* las3_t;

__device__ __forceinline__ unsigned pk2(float a, float b) {
    __hip_bfloat162 h = __float22bfloat162_rn(make_float2(a, b));
    return *reinterpret_cast<unsigned*>(&h);
}

__global__ __launch_bounds__(256) void pack_A(
    const float* __restrict__ xf,
    bf16x8* __restrict__ Bp)
{
    const int slot = blockIdx.x * 256 + threadIdx.x;
    if (slot >= NSLOT) return;

    if (slot == ZSLOT) {                       // broadcast zero slot
        union { bf16x8 v; unsigned w[4]; } z;
        z.w[0] = z.w[1] = z.w[2] = z.w[3] = 0u;
        Bp[slot] = z.v;
        return;
    }

    int s, t, l;
    if (slot < SLOTS_FULL) {
        s = slot / (NT * 64);
        const int rem = slot - s * (NT * 64);
        t = rem >> 6;
        l = rem & 63;
    } else {
        s = 6;
        const int rem = slot - SLOTS_FULL;
        t = rem >> 5;
        l = rem & 31;                          // lgrp 0/1 only
    }
    const int lgrp = l >> 4;
    const int lrow = l & 15;
    const int n = t * 16 + lrow;               // n = 3b + i, < 96
    const int b = n / 3;
    const int i = n - 3 * b;
    const int j0 = s * 8 + lgrp * 2;           // <= 50 for all stored slots

    const float4* __restrict__ xf4 = reinterpret_cast<const float4*>(xf);
    const float4 m0 = xf4[(b * J + j0) * 4 + i];
    const float4 m1 = xf4[(b * J + j0 + 1) * 4 + i];
    union { bf16x8 v; unsigned w[4]; } r;
    r.w[0] = pk2(m0.x, m0.y); r.w[1] = pk2(m0.z, m0.w);
    r.w[2] = pk2(m1.x, m1.y); r.w[3] = pk2(m1.z, m1.w);
    Bp[slot] = r.v;
}

__global__ __launch_bounds__(256, 4) void skin_mfma(
    const float* __restrict__ verts,
    const float* __restrict__ weights,
    const bf16x8* __restrict__ Bp,
    float* __restrict__ out,
    int V)
{
    __shared__ __align__(16) char sBp[LDS_B];  // 40960 B -> 4 blocks/CU

    const int tid  = threadIdx.x;
    const int lane = tid & 63;
    const int wid  = tid >> 6;
    const int lgrp = lane >> 4;
    const int lrow = lane & 15;
    const int v0   = blockIdx.x * VPB;

    // ---- issue A-stage: 40 KB linear, wave-striped 1KB chunks ----
    {
        const char* g = (const char*)Bp;
        for (int p = wid; p < LDS_B / 1024; p += WAVES) {
            __builtin_amdgcn_global_load_lds(
                (gas1_t)(g + p * 1024 + lane * 16),
                (las3_t)(sBp + p * 1024), 16, 0, 0);
        }
    }

    // ---- reg loads in the stage's shadow (verts + weights) ----
    int   vv[MT];
    bool  vok[MT];
    float hx[MT], hy[MT], hz[MT];
    float2 wv[MT][KSTEPS];
#pragma unroll
    for (int mt = 0; mt < MT; ++mt) {
        const int v = v0 + wid * VPW + mt * 16 + lrow;
        vv[mt]  = v;
        vok[mt] = (v < V);
        const int vcl = vok[mt] ? v : (V - 1);   // clamped lanes never stored
        hx[mt] = verts[3 * (size_t)vcl + 0];
        hy[mt] = verts[3 * (size_t)vcl + 1];
        hz[mt] = verts[3 * (size_t)vcl + 2];
        const float* wr = weights + (size_t)vcl * J;
#pragma unroll
        for (int s = 0; s < KSTEPS; ++s) {
            const int j0 = s * 8 + lgrp * 2;     // only s=6, lgrp>=2 exceeds J
            wv[mt][s] = (j0 < J) ? *(const float2*)(wr + j0) : float2{0.f, 0.f};
        }
    }

    __syncthreads();

    // ---- k-loop: pure LDS + VALU + MFMA ----
    f32x4 acc[MT][NT];
#pragma unroll
    for (int mt = 0; mt < MT; ++mt)
#pragma unroll
        for (int t = 0; t < NT; ++t)
            acc[mt][t] = f32x4{0.f, 0.f, 0.f, 0.f};

#pragma unroll
    for (int s = 0; s < KSTEPS; ++s) {
        bf16x8 frag[NT];
#pragma unroll
        for (int t = 0; t < NT; ++t) {
            if (s < 6) {
                frag[t] = *(const bf16x8*)(sBp + ((s * NT + t) * 64 + lane) * 16);
            } else {
                const char* p = (lane < 32)
                    ? (sBp + S6_BASE_B + (t * 32 + lane) * 16)
                    : (sBp + Z_B);               // 32-lane broadcast of zeros
                frag[t] = *(const bf16x8*)p;
            }
        }
#pragma unroll
        for (int mt = 0; mt < MT; ++mt) {
            const float w0 = wv[mt][s].x, w1 = wv[mt][s].y;
            union { bf16x8 v; unsigned w[4]; } xf8;
            xf8.w[0] = pk2(w0 * hx[mt], w0 * hy[mt]);
            xf8.w[1] = pk2(w0 * hz[mt], w0);
            xf8.w[2] = pk2(w1 * hx[mt], w1 * hy[mt]);
            xf8.w[3] = pk2(w1 * hz[mt], w1);
#pragma unroll
            for (int t = 0; t < NT; ++t) {
                // SWAPPED: A = matrix (rows n), B = X (cols v)
                acc[mt][t] = __builtin_amdgcn_mfma_f32_16x16x32_bf16(
                    frag[t], xf8.v, acc[mt][t], 0, 0, 0);
            }
        }
    }

    // ---- store: lane holds D[n = 16t + lgrp*4 + r][v], v = col = lane&15 ----
#pragma unroll
    for (int mt = 0; mt < MT; ++mt) {
        if (!vok[mt]) continue;
        const size_t v3 = (size_t)vv[mt] * 3;
#pragma unroll
        for (int t = 0; t < NT; ++t) {
#pragma unroll
            for (int r = 0; r < 4; ++r) {
                const int n = 16 * t + lgrp * 4 + r;
                const int b = n / 3;
                const int i = n - 3 * b;
                out[(size_t)b * (size_t)V * 3 + v3 + i] = acc[mt][t][r];
            }
        }
    }
}

extern "C" void kernel_launch(void* const* d_in, const int* in_sizes, int n_in,
                              void* d_out, int out_size, void* d_ws, size_t ws_size,
                              hipStream_t stream)
{
    const float* verts   = (const float*)d_in[0];
    const float* weights = (const float*)d_in[1];
    const float* xf      = (const float*)d_in[2];
    float* out = (float*)d_out;

    const int V = in_sizes[0] / 3;   // 100000
    bf16x8* Bp = (bf16x8*)d_ws;      // 39952 B written; 40960 B staged

    pack_A<<<(NSLOT + 255) / 256, 256, 0, stream>>>(xf, Bp);
    const int nblocks = (V + VPB - 1) / VPB;
    skin_mfma<<<nblocks, 256, 0, stream>>>(verts, weights, Bp, out, V);
}

// Round 8
// 25.902 us; speedup vs baseline: 1.9043x; 1.1081x over previous
//
#include <hip/hip_runtime.h>
#include <hip/hip_bf16.h>

// LBS skinning as bf16 MFMA GEMM (swapped operands), two-phase:
//   Phase 1 (pack_A): pack A[k=4j+c][n=3b+i] = M[b,j,i,c] into MFMA
//     A-operand fragment lane order in d_ws (43008 B, L2-resident).
//   Phase 2 (skin_mfma): D[n][v] = sum_k A[k,n] * X[v,k],
//     X[v,4j+c] = w[v,j]*h_v[c], h=(x,y,z,1).
//   NEW: LDS-transpose epilogue -- acc is bounced through LDS into the
//   exact out-region layout and stored as contiguous dwordx4 (1536 B
//   per b per block), replacing 48 scattered per-lane dword stores.
// V=100000, N=96, K=208 (padded to 224 = 7 steps of 32)

typedef __attribute__((ext_vector_type(8))) short bf16x8;
typedef __attribute__((ext_vector_type(4))) float f32x4;

constexpr int J      = 52;
constexpr int KSTEPS = 7;
constexpr int NT     = 6;                  // 6 n-tiles of 16 -> N=96
constexpr int WAVES  = 4;
constexpr int MT     = 2;                  // m-tiles (16 verts) per wave
constexpr int VPW    = MT * 16;            // 32 verts per wave
constexpr int VPB    = WAVES * VPW;        // 128 verts per block
constexpr int NSLOT  = KSTEPS * NT * 64;   // 2688 fragment slots
constexpr int BP_B   = NSLOT * 16;         // 43008 B
constexpr int OUT_B  = 16 * VPB * 3 * 4;   // 24576 B (one 16-batch half)

typedef const __attribute__((address_space(1))) char* gas1_t;
typedef __attribute__((address_space(3))) char* las3_t;

__device__ __forceinline__ unsigned pk2(float a, float b) {
    __hip_bfloat162 h = __float22bfloat162_rn(make_float2(a, b));
    return *reinterpret_cast<unsigned*>(&h);
}

__global__ __launch_bounds__(256) void pack_A(
    const float* __restrict__ xf,
    bf16x8* __restrict__ Bp)
{
    const int slot = blockIdx.x * 256 + threadIdx.x;
    if (slot >= NSLOT) return;
    const int s    = slot / (NT * 64);
    const int rem  = slot - s * (NT * 64);
    const int t    = rem >> 6;
    const int l    = rem & 63;
    const int lgrp = l >> 4;
    const int lrow = l & 15;
    const int n = t * 16 + lrow;          // n = 3b + i, always < 96
    const int b = n / 3;
    const int i = n - 3 * b;
    const int j0 = s * 8 + lgrp * 2;      // elems 0-3 -> joint j0, 4-7 -> j0+1
    const float4* __restrict__ xf4 = reinterpret_cast<const float4*>(xf);
    float4 m0 = {0,0,0,0}, m1 = {0,0,0,0};
    if (j0 < J)     m0 = xf4[(b * J + j0) * 4 + i];
    if (j0 + 1 < J) m1 = xf4[(b * J + j0 + 1) * 4 + i];
    union { bf16x8 v; unsigned w[4]; } r;
    r.w[0] = pk2(m0.x, m0.y); r.w[1] = pk2(m0.z, m0.w);
    r.w[2] = pk2(m1.x, m1.y); r.w[3] = pk2(m1.z, m1.w);
    Bp[slot] = r.v;
}

__global__ __launch_bounds__(256, 2) void skin_mfma(
    const float* __restrict__ verts,
    const float* __restrict__ weights,
    const bf16x8* __restrict__ Bp,
    float* __restrict__ out,
    int V)
{
    __shared__ __align__(16) char sBp[BP_B];    // 43008 B: packed A
    __shared__ __align__(16) char sOut[OUT_B];  // 24576 B: store-transpose half

    const int tid  = threadIdx.x;
    const int lane = tid & 63;
    const int wid  = tid >> 6;
    const int lgrp = lane >> 4;
    const int lrow = lane & 15;
    const int v0   = blockIdx.x * VPB;

    // ---- issue A-stage: 43008 B linear, wave-striped 1KB chunks ----
    {
        const char* g = (const char*)Bp;
        for (int p = wid; p < BP_B / 1024; p += WAVES) {
            __builtin_amdgcn_global_load_lds(
                (gas1_t)(g + p * 1024 + lane * 16),
                (las3_t)(sBp + p * 1024), 16, 0, 0);
        }
    }

    // ---- reg loads in the stage's shadow (verts + weights) ----
    float hx[MT], hy[MT], hz[MT];
    float2 wv[MT][KSTEPS];
#pragma unroll
    for (int mt = 0; mt < MT; ++mt) {
        const int v   = v0 + wid * VPW + mt * 16 + lrow;
        const int vcl = (v < V) ? v : (V - 1);   // clamped lanes never stored
        hx[mt] = verts[3 * (size_t)vcl + 0];
        hy[mt] = verts[3 * (size_t)vcl + 1];
        hz[mt] = verts[3 * (size_t)vcl + 2];
        const float* wr = weights + (size_t)vcl * J;
#pragma unroll
        for (int s = 0; s < KSTEPS; ++s) {
            const int j0 = s * 8 + lgrp * 2;
            wv[mt][s] = (j0 < J) ? *(const float2*)(wr + j0) : float2{0.f, 0.f};
        }
    }

    __syncthreads();

    // ---- k-loop: pure LDS + VALU + MFMA ----
    f32x4 acc[MT][NT];
#pragma unroll
    for (int mt = 0; mt < MT; ++mt)
#pragma unroll
        for (int t = 0; t < NT; ++t)
            acc[mt][t] = f32x4{0.f, 0.f, 0.f, 0.f};

#pragma unroll
    for (int s = 0; s < KSTEPS; ++s) {
        bf16x8 frag[NT];
#pragma unroll
        for (int t = 0; t < NT; ++t)
            frag[t] = *(const bf16x8*)(sBp + ((s * NT + t) * 64 + lane) * 16);
#pragma unroll
        for (int mt = 0; mt < MT; ++mt) {
            const float w0 = wv[mt][s].x, w1 = wv[mt][s].y;
            union { bf16x8 v; unsigned w[4]; } xf8;
            xf8.w[0] = pk2(w0 * hx[mt], w0 * hy[mt]);
            xf8.w[1] = pk2(w0 * hz[mt], w0);
            xf8.w[2] = pk2(w1 * hx[mt], w1 * hy[mt]);
            xf8.w[3] = pk2(w1 * hz[mt], w1);
#pragma unroll
            for (int t = 0; t < NT; ++t) {
                // SWAPPED: A = matrix (rows n), B = X (cols v)
                acc[mt][t] = __builtin_amdgcn_mfma_f32_16x16x32_bf16(
                    frag[t], xf8.v, acc[mt][t], 0, 0, 0);
            }
        }
    }

    // ---- epilogue: LDS transpose -> contiguous dwordx4 stores ----
    // Lane holds D[n = 16t + lgrp*4 + r][v = v0 + wid*32 + mt*16 + lrow].
    // Half h covers t in [3h, 3h+3) -> n in [48h, 48h+48) -> b in [16h,16h+16).
    // sOut float layout == out region: ((b-16h)*VPB + vloc)*3 + i.
    const long long validf = ((long long)V - v0) * 3;   // valid floats per b
#pragma unroll
    for (int h = 0; h < 2; ++h) {
        __syncthreads();   // sOut free (prev read done / first entry)
#pragma unroll
        for (int mt = 0; mt < MT; ++mt) {
            const int vloc = wid * VPW + mt * 16 + lrow;
#pragma unroll
            for (int tt = 0; tt < 3; ++tt) {
                const int t = 3 * h + tt;
#pragma unroll
                for (int r = 0; r < 4; ++r) {
                    const int n  = 16 * t + lgrp * 4 + r;
                    const int b  = n / 3;
                    const int i  = n - 3 * b;
                    const int fl = ((b - 16 * h) * VPB + vloc) * 3 + i;
                    *(float*)(sOut + fl * 4) = acc[mt][t][r];
                }
            }
        }
        __syncthreads();   // half h fully written
        // read back linearly, store contiguous float4 runs (1536 B per b)
#pragma unroll
        for (int q = 0; q < 6; ++q) {
            const int idx = q * 256 + tid;          // 0..1535
            const int bl  = idx / 96;               // local b (0..15)
            const int rr  = idx - bl * 96;          // float4 index within b
            const f32x4 val = *(const f32x4*)(sOut + (bl * 96 + rr) * 16);
            if ((long long)rr * 4 + 4 <= validf) {
                const int b = 16 * h + bl;
                float4* dst = (float4*)(out + (size_t)b * (size_t)V * 3
                                            + (size_t)v0 * 3) + rr;
                *dst = *(const float4*)&val;
            }
        }
    }
}

extern "C" void kernel_launch(void* const* d_in, const int* in_sizes, int n_in,
                              void* d_out, int out_size, void* d_ws, size_t ws_size,
                              hipStream_t stream)
{
    const float* verts   = (const float*)d_in[0];
    const float* weights = (const float*)d_in[1];
    const float* xf      = (const float*)d_in[2];
    float* out = (float*)d_out;

    const int V = in_sizes[0] / 3;   // 100000
    bf16x8* Bp = (bf16x8*)d_ws;      // 43008 bytes

    pack_A<<<(NSLOT + 255) / 256, 256, 0, stream>>>(xf, Bp);
    const int nblocks = (V + VPB - 1) / VPB;
    skin_mfma<<<nblocks, 256, 0, stream>>>(verts, weights, Bp, out, V);
}